// Round 7
// baseline (691.631 us; speedup 1.0000x reference)
//
#include <hip/hip_runtime.h>
#include <hip/hip_cooperative_groups.h>

namespace cg = cooperative_groups;

// B=256, S=512, H=1024, L=30
// out = [tanh(x0)|tanh(mean_sub)|tanh(mean_obj)] @ Wfold + btot
//   P1 = W_d2@W_out; Wd1o = W_d1@P1; Wfold[z] = W_z@Wd1o[z]
//   btot = b_out + b_d2@W_out + b_d1@P1 + [b_cls|b_e1|b_e2]@Wd1o
// One kernel body with 4 phases:
//   0: span partials (CH=64) + fold1 (P1T transposed out)
//   1: fold2 (Wd1oT transposed out; coalesced reads of P1T)
//   2: fold3 (Wf row-major padded; coalesced reads of Wd1oT) + bias rows
//   3: final per-batch dot
// Launched EITHER as one cooperative kernel (grid.sync between phases) OR,
// if cooperative launch is unavailable, as 4 plain launches (fallback).
// Fold pattern: one wave per output row, lane l owns k in [16l,16l+16),
// 30 VGPR accumulators, 64-lane butterfly reduce.

#define B_ 256
#define S_ 512
#define H_ 1024
#define L_ 30
#define CH 64
#define NCHUNK 8
#define GRID 512
#define SPAN_ITEMS (B_ * 2 * NCHUNK)  // 4096

__device__ __forceinline__ void reduce30_butterfly(float* acc) {
#pragma unroll
  for (int n = 0; n < 30; ++n) {
#pragma unroll
    for (int m = 1; m < 64; m <<= 1) acc[n] += __shfl_xor(acc[n], m);
  }
}

// acc[n] += arow . ST[n][soff..soff+1024) ; ST transposed, row stride sstride.
__device__ __forceinline__ void fold_row_T(
    const float* __restrict__ arow, const float* __restrict__ ST,
    size_t sstride, size_t soff, float* acc, int lane) {
  const float* a = arow + lane * 16;
  float4 a4[4];
#pragma unroll
  for (int g = 0; g < 4; ++g) a4[g] = *(const float4*)(a + 4 * g);
  const float* sbase = ST + soff + (size_t)lane * 16;
#pragma unroll
  for (int g = 0; g < 4; ++g) {
#pragma unroll
    for (int n = 0; n < 30; ++n) {
      float4 s4 = *(const float4*)(sbase + (size_t)n * sstride + 4 * g);
      acc[n] += a4[g].x * s4.x + a4[g].y * s4.y + a4[g].z * s4.z + a4[g].w * s4.w;
    }
  }
}

// acc[n] += arow . S[:,n] with S row-major stride 30 (W_out). Scalar s-reads
// (120 B contiguous per (lane,k) -> lines fully consumed).
__device__ __forceinline__ void fold_row_RM30(
    const float* __restrict__ arow, const float* __restrict__ S,
    float* acc, int lane) {
  const float* a = arow + lane * 16;
#pragma unroll
  for (int j = 0; j < 16; ++j) {
    const float av = a[j];
    const float* srow = S + (size_t)(lane * 16 + j) * 30;
#pragma unroll
    for (int n = 0; n < 30; ++n) acc[n] += av * srow[n];
  }
}

__global__ __launch_bounds__(256, 2) void mega_kernel(
    const float* __restrict__ x, const int* __restrict__ eidx,
    const float* __restrict__ W_cls, const float* __restrict__ b_cls,
    const float* __restrict__ W_e1, const float* __restrict__ b_e1,
    const float* __restrict__ W_e2, const float* __restrict__ b_e2,
    const float* __restrict__ W_d1, const float* __restrict__ b_d1,
    const float* __restrict__ W_d2, const float* __restrict__ b_d2,
    const float* __restrict__ W_out, const float* __restrict__ b_out,
    float* __restrict__ Pspan, float* __restrict__ P1T,
    float* __restrict__ Wd1oT, float* __restrict__ Wf,
    float* __restrict__ rbias, float* __restrict__ out,
    int p0, int p1, int multi) {
  const int bid = blockIdx.x;
  const int t = threadIdx.x;
  const int wid = t >> 6, lane = t & 63;

  __shared__ float Ts[3 * H_];
  __shared__ float red[8][30];

  for (int phase = p0; phase < p1; ++phase) {
    if (phase == 0) {
      // ---------------- Phase 0: span partials + fold1 ----------------
      for (int it = bid; it < SPAN_ITEMS + H_ / 4; it += GRID) {
        if (it < SPAN_ITEMS) {
          const int b = it >> 4;
          const int role = (it >> 3) & 1;
          const int chunk = it & 7;
          const int lo = eidx[b * 4 + 2 * role];
          const int hi = eidx[b * 4 + 2 * role + 1];
          int s0 = max(lo, chunk * CH);
          int s1 = min(hi, chunk * CH + CH);
          if (s0 < s1) {
            const int col = t * 4;
            const float* base = x + (size_t)b * S_ * H_ + col;
            float x0 = 0.f, y0 = 0.f, z0 = 0.f, w0 = 0.f;
            float x1 = 0.f, y1 = 0.f, z1 = 0.f, w1 = 0.f;
            float x2 = 0.f, y2 = 0.f, z2 = 0.f, w2 = 0.f;
            float x3 = 0.f, y3 = 0.f, z3 = 0.f, w3 = 0.f;
            int s = s0;
            for (; s + 4 <= s1; s += 4) {
              float4 v0 = *(const float4*)(base + (size_t)s * H_);
              float4 v1 = *(const float4*)(base + (size_t)(s + 1) * H_);
              float4 v2 = *(const float4*)(base + (size_t)(s + 2) * H_);
              float4 v3 = *(const float4*)(base + (size_t)(s + 3) * H_);
              x0 += v0.x; y0 += v0.y; z0 += v0.z; w0 += v0.w;
              x1 += v1.x; y1 += v1.y; z1 += v1.z; w1 += v1.w;
              x2 += v2.x; y2 += v2.y; z2 += v2.z; w2 += v2.w;
              x3 += v3.x; y3 += v3.y; z3 += v3.z; w3 += v3.w;
            }
            for (; s < s1; ++s) {
              float4 v = *(const float4*)(base + (size_t)s * H_);
              x0 += v.x; y0 += v.y; z0 += v.z; w0 += v.w;
            }
            float4 o;
            o.x = x0 + x1 + x2 + x3;
            o.y = y0 + y1 + y2 + y3;
            o.z = z0 + z1 + z2 + z3;
            o.w = w0 + w1 + w2 + w3;
            *(float4*)(Pspan + (((size_t)b * 2 + role) * NCHUNK + chunk) * H_ + col) = o;
          }
        } else {
          // fold1: P1T[n][row] = W_d2[row,:] . W_out[:,n]
          const int row = (it - SPAN_ITEMS) * 4 + wid;  // 0..1023
          float acc[30];
#pragma unroll
          for (int n = 0; n < 30; ++n) acc[n] = 0.f;
          fold_row_RM30(W_d2 + (size_t)row * H_, W_out, acc, lane);
          reduce30_butterfly(acc);
          if (lane == 0) {
#pragma unroll
            for (int n = 0; n < 30; ++n) P1T[(size_t)n * H_ + row] = acc[n];
          }
        }
      }
    } else if (phase == 1) {
      // ---------------- Phase 1: fold2 -> Wd1oT ----------------
      for (int it = bid; it < 768; it += GRID) {
        const int row = it * 4 + wid;  // 0..3071
        float acc[30];
#pragma unroll
        for (int n = 0; n < 30; ++n) acc[n] = 0.f;
        fold_row_T(W_d1 + (size_t)row * H_, P1T, H_, 0, acc, lane);
        reduce30_butterfly(acc);
        if (lane == 0) {
#pragma unroll
          for (int n = 0; n < 30; ++n) Wd1oT[(size_t)n * (3 * H_) + row] = acc[n];
        }
      }
    } else if (phase == 2) {
      // ---------------- Phase 2: fold3 -> Wf, + bias rows ----------------
      for (int it = bid; it < 769; it += GRID) {
        if (it < 768) {
          const int row = it * 4 + wid;  // 0..3071
          const int z = row >> 10, r = row & (H_ - 1);
          const float* A = (z == 0) ? W_cls : (z == 1) ? W_e1 : W_e2;
          float acc[30];
#pragma unroll
          for (int n = 0; n < 30; ++n) acc[n] = 0.f;
          fold_row_T(A + (size_t)r * H_, Wd1oT, 3 * H_, (size_t)z * H_, acc, lane);
          reduce30_butterfly(acc);
          if (lane == 0) {
#pragma unroll
            for (int n = 0; n < 30; ++n) Wf[(size_t)row * 32 + n] = acc[n];
          }
        } else if (wid == 0) {
          // rbias[0..29] = [b_cls|b_e1|b_e2] . Wd1o (K=3072, lane owns 48)
          float acc[30];
#pragma unroll
          for (int n = 0; n < 30; ++n) acc[n] = 0.f;
          const int kbase = lane * 48;
#pragma unroll
          for (int g = 0; g < 12; ++g) {
            const int idx = kbase + g * 4;
            const float* bsrc = (idx < 1024) ? (b_cls + idx)
                              : (idx < 2048) ? (b_e1 + idx - 1024)
                                             : (b_e2 + idx - 2048);
            float4 bv = *(const float4*)bsrc;
            const float* sb = Wd1oT + idx;
#pragma unroll
            for (int n = 0; n < 30; ++n) {
              float4 s4 = *(const float4*)(sb + (size_t)n * (3 * H_));
              acc[n] += bv.x * s4.x + bv.y * s4.y + bv.z * s4.z + bv.w * s4.w;
            }
          }
          reduce30_butterfly(acc);
          if (lane == 0) {
#pragma unroll
            for (int n = 0; n < 30; ++n) rbias[n] = acc[n];
          }
        } else if (wid == 1) {
          float acc[30];
#pragma unroll
          for (int n = 0; n < 30; ++n) acc[n] = 0.f;
          fold_row_T(b_d1, P1T, H_, 0, acc, lane);
          reduce30_butterfly(acc);
          if (lane == 0) {
#pragma unroll
            for (int n = 0; n < 30; ++n) rbias[32 + n] = acc[n];
          }
        } else if (wid == 2) {
          float acc[30];
#pragma unroll
          for (int n = 0; n < 30; ++n) acc[n] = 0.f;
          fold_row_RM30(b_d2, W_out, acc, lane);
          reduce30_butterfly(acc);
          if (lane == 0) {
#pragma unroll
            for (int n = 0; n < 30; ++n) rbias[64 + n] = acc[n];
          }
        }
      }
    } else {
      // ---------------- Phase 3: final ----------------
      for (int it = bid; it < B_; it += GRID) {
        const int b = it;
        const int col = t * 4;
        {
          float4 v = *(const float4*)(x + (size_t)b * S_ * H_ + col);
          Ts[col + 0] = tanhf(v.x);
          Ts[col + 1] = tanhf(v.y);
          Ts[col + 2] = tanhf(v.z);
          Ts[col + 3] = tanhf(v.w);
        }
#pragma unroll
        for (int role = 0; role < 2; ++role) {
          const int lo = eidx[b * 4 + 2 * role];
          const int hi = eidx[b * 4 + 2 * role + 1];
          const int c0 = lo >> 6;
          const int c1 = (hi - 1) >> 6;
          float ax = 0.f, ay = 0.f, az = 0.f, aw = 0.f;
          for (int c = c0; c <= c1; ++c) {
            float4 v = *(const float4*)(Pspan + (((size_t)b * 2 + role) * NCHUNK + c) * H_ + col);
            ax += v.x; ay += v.y; az += v.z; aw += v.w;
          }
          const float inv = 1.0f / (float)(hi - lo);
          float* Td = Ts + (1 + role) * H_ + col;
          Td[0] = tanhf(ax * inv);
          Td[1] = tanhf(ay * inv);
          Td[2] = tanhf(az * inv);
          Td[3] = tanhf(aw * inv);
        }
        __syncthreads();

        if (t < 240) {
          const int n = t % 30, p = t / 30;
          const int k0 = p * 384;
          float s = 0.f;
#pragma unroll 4
          for (int k = k0; k < k0 + 384; ++k) s += Ts[k] * Wf[(size_t)k * 32 + n];
          red[p][n] = s;
        }
        __syncthreads();
        if (t < L_) {
          float s = b_out[t] + rbias[t] + rbias[32 + t] + rbias[64 + t];
#pragma unroll
          for (int p = 0; p < 8; ++p) s += red[p][t];
          out[(size_t)b * L_ + t] = s;
        }
        __syncthreads();
      }
    }
    if (multi && phase + 1 < p1) cg::this_grid().sync();
  }
}

extern "C" void kernel_launch(void* const* d_in, const int* in_sizes, int n_in,
                              void* d_out, int out_size, void* d_ws, size_t ws_size,
                              hipStream_t stream) {
  const float* x = (const float*)d_in[0];
  const int* eidx = (const int*)d_in[1];
  const float* W_cls = (const float*)d_in[2];
  const float* b_cls = (const float*)d_in[3];
  const float* W_e1 = (const float*)d_in[4];
  const float* b_e1 = (const float*)d_in[5];
  const float* W_e2 = (const float*)d_in[6];
  const float* b_e2 = (const float*)d_in[7];
  const float* W_d1 = (const float*)d_in[8];
  const float* b_d1 = (const float*)d_in[9];
  const float* W_d2 = (const float*)d_in[10];
  const float* b_d2 = (const float*)d_in[11];
  const float* W_out = (const float*)d_in[12];
  const float* b_out = (const float*)d_in[13];
  float* out = (float*)d_out;

  float* ws = (float*)d_ws;
  float* Pspan = ws;                   // 256*2*8*1024 = 4,194,304
  float* P1T   = Pspan + 4194304;      // 30*1024 = 30,720
  float* Wd1oT = P1T + 30720;          // 30*3072 = 92,160
  float* Wf    = Wd1oT + 92160;        // 3072*32 = 98,304
  float* rbias = Wf + 98304;           // 96
  // total ~4.4M floats ~17.7 MB

  int p0 = 0, p1 = 4, multi = 1;
  void* kargs[] = {
      (void*)&x, (void*)&eidx,
      (void*)&W_cls, (void*)&b_cls, (void*)&W_e1, (void*)&b_e1,
      (void*)&W_e2, (void*)&b_e2, (void*)&W_d1, (void*)&b_d1,
      (void*)&W_d2, (void*)&b_d2, (void*)&W_out, (void*)&b_out,
      (void*)&Pspan, (void*)&P1T, (void*)&Wd1oT, (void*)&Wf,
      (void*)&rbias, (void*)&out, (void*)&p0, (void*)&p1, (void*)&multi};

  hipError_t err = hipLaunchCooperativeKernel(
      (const void*)mega_kernel, dim3(GRID), dim3(256), kargs, 0, stream);

  if (err != hipSuccess) {
    (void)hipGetLastError();  // clear sticky error, fall back to 4 launches
    mega_kernel<<<GRID, 256, 0, stream>>>(
        x, eidx, W_cls, b_cls, W_e1, b_e1, W_e2, b_e2, W_d1, b_d1,
        W_d2, b_d2, W_out, b_out, Pspan, P1T, Wd1oT, Wf, rbias, out, 0, 1, 0);
    mega_kernel<<<GRID, 256, 0, stream>>>(
        x, eidx, W_cls, b_cls, W_e1, b_e1, W_e2, b_e2, W_d1, b_d1,
        W_d2, b_d2, W_out, b_out, Pspan, P1T, Wd1oT, Wf, rbias, out, 1, 2, 0);
    mega_kernel<<<GRID, 256, 0, stream>>>(
        x, eidx, W_cls, b_cls, W_e1, b_e1, W_e2, b_e2, W_d1, b_d1,
        W_d2, b_d2, W_out, b_out, Pspan, P1T, Wd1oT, Wf, rbias, out, 2, 3, 0);
    mega_kernel<<<GRID, 256, 0, stream>>>(
        x, eidx, W_cls, b_cls, W_e1, b_e1, W_e2, b_e2, W_d1, b_d1,
        W_d2, b_d2, W_out, b_out, Pspan, P1T, Wd1oT, Wf, rbias, out, 3, 4, 0);
  }
}

// Round 8
// 240.567 us; speedup vs baseline: 2.8750x; 2.8750x over previous
//
#include <hip/hip_runtime.h>
#include <hip/hip_bf16.h>

// B=256, S=512, H=1024, L=30
// out = [tanh(x0)|tanh(mean_sub)|tanh(mean_obj)] @ Wfold + btot
//   P1 = W_d2@W_out; Wd1o = W_d1@P1; Wfold[z] = W_z@Wd1o[z]
//   btot = b_out + b_d2@W_out + b_d1@P1 + [b_cls|b_e1|b_e2]@Wd1o
// 5 launches: span(+W_out transpose tail), fold1, fold2, fold3(+bias), final.
// Folds: ONE WAVE PER OUTPUT ROW (64-thread block, launch_bounds(64): no
// VGPR cap -> no spills). S operands pre-transposed so every wave fold read
// is a contiguous 4KB b128 stream (fixes R5's 2KB-lane-stride L2 blowup;
// fixes R7's spill storm: R7 had WRITE_SIZE=358MB, VGPR clamped at 128).

#define B_ 256
#define S_ 512
#define H_ 1024
#define L_ 30
#define CH 64
#define NCHUNK 8

// ---------------------------------------------------------------------------
// acc[n] += arow[0..1023] . ST[n][soff..soff+1024); ST transposed, stride sstride.
// Lane l owns k in [16l, 16l+16). All reads contiguous 4KB per wave instr.
// ---------------------------------------------------------------------------
__device__ __forceinline__ void fold_row_T(
    const float* __restrict__ arow, const float* __restrict__ ST,
    size_t sstride, size_t soff, float* acc, int lane) {
  const float* a = arow + lane * 16;
  float4 a4[4];
#pragma unroll
  for (int g = 0; g < 4; ++g) a4[g] = *(const float4*)(a + 4 * g);
  const float* sbase = ST + soff + (size_t)lane * 16;
#pragma unroll
  for (int g = 0; g < 4; ++g) {
#pragma unroll
    for (int n = 0; n < 30; ++n) {
      float4 s4 = *(const float4*)(sbase + (size_t)n * sstride + 4 * g);
      acc[n] += a4[g].x * s4.x + a4[g].y * s4.y + a4[g].z * s4.z + a4[g].w * s4.w;
    }
  }
}

__device__ __forceinline__ void reduce30_butterfly(float* acc) {
#pragma unroll
  for (int n = 0; n < 30; ++n) {
#pragma unroll
    for (int m = 1; m < 64; m <<= 1) acc[n] += __shfl_xor(acc[n], m);
  }
}

// ---------------------------------------------------------------------------
// Span partials (grid B x NCHUNK+1 x 2, block 256). chunk==NCHUNK tail blocks
// transpose W_out -> WoutT[30][1024].
// ---------------------------------------------------------------------------
__global__ __launch_bounds__(256) void span_kernel(
    const float* __restrict__ x, const int* __restrict__ eidx,
    const float* __restrict__ W_out,
    float* __restrict__ Pspan, float* __restrict__ WoutT) {
  const int b = blockIdx.x;
  const int chunk = blockIdx.y;
  const int role = blockIdx.z;
  const int t = threadIdx.x;

  if (chunk == NCHUNK) {
    if (role == 0 && b < 120) {
      int idx = b * 256 + t;
      if (idx < H_ * L_) {
        int k = idx / L_, n = idx - k * L_;
        WoutT[(size_t)n * H_ + k] = W_out[idx];
      }
    }
    return;
  }

  const int lo = eidx[b * 4 + 2 * role];
  const int hi = eidx[b * 4 + 2 * role + 1];
  int s0 = max(lo, chunk * CH);
  int s1 = min(hi, chunk * CH + CH);
  if (s0 >= s1) return;

  const int col = t * 4;
  const float* base = x + (size_t)b * S_ * H_ + col;
  float x0 = 0.f, y0 = 0.f, z0 = 0.f, w0 = 0.f;
  float x1 = 0.f, y1 = 0.f, z1 = 0.f, w1 = 0.f;
  float x2 = 0.f, y2 = 0.f, z2 = 0.f, w2 = 0.f;
  float x3 = 0.f, y3 = 0.f, z3 = 0.f, w3 = 0.f;
  int s = s0;
  for (; s + 4 <= s1; s += 4) {
    float4 v0 = *(const float4*)(base + (size_t)s * H_);
    float4 v1 = *(const float4*)(base + (size_t)(s + 1) * H_);
    float4 v2 = *(const float4*)(base + (size_t)(s + 2) * H_);
    float4 v3 = *(const float4*)(base + (size_t)(s + 3) * H_);
    x0 += v0.x; y0 += v0.y; z0 += v0.z; w0 += v0.w;
    x1 += v1.x; y1 += v1.y; z1 += v1.z; w1 += v1.w;
    x2 += v2.x; y2 += v2.y; z2 += v2.z; w2 += v2.w;
    x3 += v3.x; y3 += v3.y; z3 += v3.z; w3 += v3.w;
  }
  for (; s < s1; ++s) {
    float4 v = *(const float4*)(base + (size_t)s * H_);
    x0 += v.x; y0 += v.y; z0 += v.z; w0 += v.w;
  }
  float4 o;
  o.x = x0 + x1 + x2 + x3;
  o.y = y0 + y1 + y2 + y3;
  o.z = z0 + z1 + z2 + z3;
  o.w = w0 + w1 + w2 + w3;
  *(float4*)(Pspan + (((size_t)b * 2 + role) * NCHUNK + chunk) * H_ + col) = o;
}

// ---------------------------------------------------------------------------
// fold1: P1T[n][row] = W_d2[row,:] . WoutT[n,:]   (1024 blocks, 1 wave each)
// ---------------------------------------------------------------------------
__global__ __launch_bounds__(64) void fold1_kernel(
    const float* __restrict__ W_d2, const float* __restrict__ WoutT,
    float* __restrict__ P1T) {
  const int row = blockIdx.x;
  const int lane = threadIdx.x;
  float acc[30];
#pragma unroll
  for (int n = 0; n < 30; ++n) acc[n] = 0.f;
  fold_row_T(W_d2 + (size_t)row * H_, WoutT, H_, 0, acc, lane);
  reduce30_butterfly(acc);
  if (lane == 0) {
#pragma unroll
    for (int n = 0; n < 30; ++n) P1T[(size_t)n * H_ + row] = acc[n];
  }
}

// ---------------------------------------------------------------------------
// fold2: Wd1oT[n][row] = W_d1[row,:] . P1T[n,:]   (3072 blocks)
// ---------------------------------------------------------------------------
__global__ __launch_bounds__(64) void fold2_kernel(
    const float* __restrict__ W_d1, const float* __restrict__ P1T,
    float* __restrict__ Wd1oT) {
  const int row = blockIdx.x;
  const int lane = threadIdx.x;
  float acc[30];
#pragma unroll
  for (int n = 0; n < 30; ++n) acc[n] = 0.f;
  fold_row_T(W_d1 + (size_t)row * H_, P1T, H_, 0, acc, lane);
  reduce30_butterfly(acc);
  if (lane == 0) {
#pragma unroll
    for (int n = 0; n < 30; ++n) Wd1oT[(size_t)n * (3 * H_) + row] = acc[n];
  }
}

// ---------------------------------------------------------------------------
// fold3: Wf[row][n] = W_z[r,:] . Wd1oT[n, z*H..] (3072 blocks) + 3 bias blocks
// ---------------------------------------------------------------------------
__global__ __launch_bounds__(64) void fold3_kernel(
    const float* __restrict__ W_cls, const float* __restrict__ W_e1,
    const float* __restrict__ W_e2, const float* __restrict__ Wd1oT,
    const float* __restrict__ P1T, const float* __restrict__ WoutT,
    const float* __restrict__ b_cls, const float* __restrict__ b_e1,
    const float* __restrict__ b_e2, const float* __restrict__ b_d1,
    const float* __restrict__ b_d2,
    float* __restrict__ Wf, float* __restrict__ rbias) {
  const int lane = threadIdx.x;
  float acc[30];
#pragma unroll
  for (int n = 0; n < 30; ++n) acc[n] = 0.f;

  if (blockIdx.x < 3 * H_) {
    const int row = blockIdx.x;
    const int z = row >> 10, r = row & (H_ - 1);
    const float* A = (z == 0) ? W_cls : (z == 1) ? W_e1 : W_e2;
    fold_row_T(A + (size_t)r * H_, Wd1oT, 3 * H_, (size_t)z * H_, acc, lane);
    reduce30_butterfly(acc);
    if (lane == 0) {
#pragma unroll
      for (int n = 0; n < 30; ++n) Wf[(size_t)row * 32 + n] = acc[n];
    }
    return;
  }
  const int which = blockIdx.x - 3 * H_;
  if (which == 0) {
    // rbias[0..29] = [b_cls|b_e1|b_e2] . Wd1o  (K=3072, lane owns 48)
    const int kbase = lane * 48;
#pragma unroll
    for (int g = 0; g < 12; ++g) {
      const int idx = kbase + g * 4;
      const float* bsrc = (idx < 1024) ? (b_cls + idx)
                        : (idx < 2048) ? (b_e1 + idx - 1024)
                                       : (b_e2 + idx - 2048);
      float4 bv = *(const float4*)bsrc;
      const float* sb = Wd1oT + idx;
#pragma unroll
      for (int n = 0; n < 30; ++n) {
        float4 s4 = *(const float4*)(sb + (size_t)n * (3 * H_));
        acc[n] += bv.x * s4.x + bv.y * s4.y + bv.z * s4.z + bv.w * s4.w;
      }
    }
    reduce30_butterfly(acc);
    if (lane == 0) {
#pragma unroll
      for (int n = 0; n < 30; ++n) rbias[n] = acc[n];
    }
  } else if (which == 1) {
    fold_row_T(b_d1, P1T, H_, 0, acc, lane);
    reduce30_butterfly(acc);
    if (lane == 0) {
#pragma unroll
      for (int n = 0; n < 30; ++n) rbias[32 + n] = acc[n];
    }
  } else {
    fold_row_T(b_d2, WoutT, H_, 0, acc, lane);
    reduce30_butterfly(acc);
    if (lane == 0) {
#pragma unroll
      for (int n = 0; n < 30; ++n) rbias[64 + n] = acc[n];
    }
  }
}

// ---------------------------------------------------------------------------
// Final: T[b] in LDS (tanh(x0), tanh(span means from partials)), then
// out[b][n] = T[b] . Wf[:,n] + btot[n].  grid B, block 256.
// ---------------------------------------------------------------------------
__global__ __launch_bounds__(256) void final_kernel(
    const float* __restrict__ x, const int* __restrict__ eidx,
    const float* __restrict__ Pspan, const float* __restrict__ Wf,
    const float* __restrict__ b_out, const float* __restrict__ rbias,
    float* __restrict__ out) {
  __shared__ float Ts[3 * H_];
  __shared__ float red[8][30];
  const int b = blockIdx.x;
  const int t = threadIdx.x;
  const int col = t * 4;

  {
    float4 v = *(const float4*)(x + (size_t)b * S_ * H_ + col);
    Ts[col + 0] = tanhf(v.x);
    Ts[col + 1] = tanhf(v.y);
    Ts[col + 2] = tanhf(v.z);
    Ts[col + 3] = tanhf(v.w);
  }
#pragma unroll
  for (int role = 0; role < 2; ++role) {
    const int lo = eidx[b * 4 + 2 * role];
    const int hi = eidx[b * 4 + 2 * role + 1];
    const int c0 = lo >> 6;
    const int c1 = (hi - 1) >> 6;
    float ax = 0.f, ay = 0.f, az = 0.f, aw = 0.f;
    for (int c = c0; c <= c1; ++c) {
      float4 v = *(const float4*)(Pspan + (((size_t)b * 2 + role) * NCHUNK + c) * H_ + col);
      ax += v.x; ay += v.y; az += v.z; aw += v.w;
    }
    const float inv = 1.0f / (float)(hi - lo);
    float* Td = Ts + (1 + role) * H_ + col;
    Td[0] = tanhf(ax * inv);
    Td[1] = tanhf(ay * inv);
    Td[2] = tanhf(az * inv);
    Td[3] = tanhf(aw * inv);
  }
  __syncthreads();

  if (t < 240) {
    const int n = t % 30, p = t / 30;
    const int k0 = p * 384;
    float s = 0.f;
#pragma unroll 4
    for (int k = k0; k < k0 + 384; ++k) s += Ts[k] * Wf[(size_t)k * 32 + n];
    red[p][n] = s;
  }
  __syncthreads();
  if (t < L_) {
    float s = b_out[t] + rbias[t] + rbias[32 + t] + rbias[64 + t];
#pragma unroll
    for (int p = 0; p < 8; ++p) s += red[p][t];
    out[(size_t)b * L_ + t] = s;
  }
}

extern "C" void kernel_launch(void* const* d_in, const int* in_sizes, int n_in,
                              void* d_out, int out_size, void* d_ws, size_t ws_size,
                              hipStream_t stream) {
  const float* x = (const float*)d_in[0];
  const int* eidx = (const int*)d_in[1];
  const float* W_cls = (const float*)d_in[2];
  const float* b_cls = (const float*)d_in[3];
  const float* W_e1 = (const float*)d_in[4];
  const float* b_e1 = (const float*)d_in[5];
  const float* W_e2 = (const float*)d_in[6];
  const float* b_e2 = (const float*)d_in[7];
  const float* W_d1 = (const float*)d_in[8];
  const float* b_d1 = (const float*)d_in[9];
  const float* W_d2 = (const float*)d_in[10];
  const float* b_d2 = (const float*)d_in[11];
  const float* W_out = (const float*)d_in[12];
  const float* b_out = (const float*)d_in[13];
  float* out = (float*)d_out;

  float* ws = (float*)d_ws;
  float* Pspan = ws;                   // 256*2*8*1024 = 4,194,304
  float* WoutT = Pspan + 4194304;      // 30*1024 = 30,720
  float* P1T   = WoutT + 30720;        // 30*1024 = 30,720
  float* Wd1oT = P1T + 30720;          // 30*3072 = 92,160
  float* Wf    = Wd1oT + 92160;        // 3072*32 = 98,304
  float* rbias = Wf + 98304;           // 96
  // total ~4.45M floats ~17.8 MB

  // span partials + W_out transpose tail
  span_kernel<<<dim3(B_, NCHUNK + 1, 2), 256, 0, stream>>>(
      x, eidx, W_out, Pspan, WoutT);

  fold1_kernel<<<H_, 64, 0, stream>>>(W_d2, WoutT, P1T);
  fold2_kernel<<<3 * H_, 64, 0, stream>>>(W_d1, P1T, Wd1oT);
  fold3_kernel<<<3 * H_ + 3, 64, 0, stream>>>(
      W_cls, W_e1, W_e2, Wd1oT, P1T, WoutT,
      b_cls, b_e1, b_e2, b_d1, b_d2, Wf, rbias);

  final_kernel<<<B_, 256, 0, stream>>>(x, eidx, Pspan, Wf, b_out, rbias, out);
}

// Round 9
// 185.639 us; speedup vs baseline: 3.7257x; 1.2959x over previous
//
#include <hip/hip_runtime.h>
#include <hip/hip_bf16.h>

// B=256, S=512, H=1024, L=30
// out = [tanh(x0)|tanh(mean_sub)|tanh(mean_obj)] @ Wfold + btot
//   P1 = W_d2@W_out; Wd1o = W_d1@P1; Wfold[z] = W_z@Wd1o[z]
//   btot = b_out + b_d2@W_out + b_d1@P1 + [b_cls|b_e1|b_e2]@Wd1o
// 5 launches: span(+W_out transpose tail), fold1, fold2, fold3(+bias), final.
// Folds: ONE WAVE PER OUTPUT ROW. Lane k-ownership = 4 chunks of 4
// (k = c*256 + 4*lane + j) so EVERY wave load instruction is 1024B
// contiguous (16 cache lines, fully consumed). R8's lane*16 layout made
// each instr touch 64 lines at 16B/line -> line-processing-bound folds.

#define B_ 256
#define S_ 512
#define H_ 1024
#define L_ 30
#define CH 64
#define NCHUNK 8

// ---------------------------------------------------------------------------
// acc[n] += arow[0..1023] . ST[n][soff..soff+1024); ST transposed, stride
// sstride. Lane l owns k in {c*256+4l..+4 : c=0..3}. All loads coalesced.
// ---------------------------------------------------------------------------
__device__ __forceinline__ void fold_row_T(
    const float* __restrict__ arow, const float* __restrict__ ST,
    size_t sstride, size_t soff, float* acc, int lane) {
  float4 a4[4];
#pragma unroll
  for (int c = 0; c < 4; ++c)
    a4[c] = *(const float4*)(arow + c * 256 + 4 * lane);
  const float* sbase = ST + soff + 4 * lane;
#pragma unroll
  for (int n = 0; n < 30; ++n) {
    const float* srow = sbase + (size_t)n * sstride;
    float s = 0.f;
#pragma unroll
    for (int c = 0; c < 4; ++c) {
      float4 s4 = *(const float4*)(srow + c * 256);
      s += a4[c].x * s4.x + a4[c].y * s4.y + a4[c].z * s4.z + a4[c].w * s4.w;
    }
    acc[n] += s;
  }
}

__device__ __forceinline__ void reduce30_butterfly(float* acc) {
#pragma unroll
  for (int n = 0; n < 30; ++n) {
#pragma unroll
    for (int m = 1; m < 64; m <<= 1) acc[n] += __shfl_xor(acc[n], m);
  }
}

// ---------------------------------------------------------------------------
// Span partials (grid B x NCHUNK+1 x 2, block 256). chunk==NCHUNK tail blocks
// transpose W_out -> WoutT[30][1024].
// ---------------------------------------------------------------------------
__global__ __launch_bounds__(256) void span_kernel(
    const float* __restrict__ x, const int* __restrict__ eidx,
    const float* __restrict__ W_out,
    float* __restrict__ Pspan, float* __restrict__ WoutT) {
  const int b = blockIdx.x;
  const int chunk = blockIdx.y;
  const int role = blockIdx.z;
  const int t = threadIdx.x;

  if (chunk == NCHUNK) {
    if (role == 0 && b < 120) {
      int idx = b * 256 + t;
      if (idx < H_ * L_) {
        int k = idx / L_, n = idx - k * L_;
        WoutT[(size_t)n * H_ + k] = W_out[idx];
      }
    }
    return;
  }

  const int lo = eidx[b * 4 + 2 * role];
  const int hi = eidx[b * 4 + 2 * role + 1];
  int s0 = max(lo, chunk * CH);
  int s1 = min(hi, chunk * CH + CH);
  if (s0 >= s1) return;

  const int col = t * 4;
  const float* base = x + (size_t)b * S_ * H_ + col;
  float x0 = 0.f, y0 = 0.f, z0 = 0.f, w0 = 0.f;
  float x1 = 0.f, y1 = 0.f, z1 = 0.f, w1 = 0.f;
  float x2 = 0.f, y2 = 0.f, z2 = 0.f, w2 = 0.f;
  float x3 = 0.f, y3 = 0.f, z3 = 0.f, w3 = 0.f;
  int s = s0;
  for (; s + 4 <= s1; s += 4) {
    float4 v0 = *(const float4*)(base + (size_t)s * H_);
    float4 v1 = *(const float4*)(base + (size_t)(s + 1) * H_);
    float4 v2 = *(const float4*)(base + (size_t)(s + 2) * H_);
    float4 v3 = *(const float4*)(base + (size_t)(s + 3) * H_);
    x0 += v0.x; y0 += v0.y; z0 += v0.z; w0 += v0.w;
    x1 += v1.x; y1 += v1.y; z1 += v1.z; w1 += v1.w;
    x2 += v2.x; y2 += v2.y; z2 += v2.z; w2 += v2.w;
    x3 += v3.x; y3 += v3.y; z3 += v3.z; w3 += v3.w;
  }
  for (; s < s1; ++s) {
    float4 v = *(const float4*)(base + (size_t)s * H_);
    x0 += v.x; y0 += v.y; z0 += v.z; w0 += v.w;
  }
  float4 o;
  o.x = x0 + x1 + x2 + x3;
  o.y = y0 + y1 + y2 + y3;
  o.z = z0 + z1 + z2 + z3;
  o.w = w0 + w1 + w2 + w3;
  *(float4*)(Pspan + (((size_t)b * 2 + role) * NCHUNK + chunk) * H_ + col) = o;
}

// ---------------------------------------------------------------------------
// fold1: P1T[n][row] = W_d2[row,:] . WoutT[n,:]   (1024 blocks, 1 wave each)
// ---------------------------------------------------------------------------
__global__ __launch_bounds__(64) void fold1_kernel(
    const float* __restrict__ W_d2, const float* __restrict__ WoutT,
    float* __restrict__ P1T) {
  const int row = blockIdx.x;
  const int lane = threadIdx.x;
  float acc[30];
#pragma unroll
  for (int n = 0; n < 30; ++n) acc[n] = 0.f;
  fold_row_T(W_d2 + (size_t)row * H_, WoutT, H_, 0, acc, lane);
  reduce30_butterfly(acc);
  if (lane == 0) {
#pragma unroll
    for (int n = 0; n < 30; ++n) P1T[(size_t)n * H_ + row] = acc[n];
  }
}

// ---------------------------------------------------------------------------
// fold2: Wd1oT[n][row] = W_d1[row,:] . P1T[n,:]   (3072 blocks)
// ---------------------------------------------------------------------------
__global__ __launch_bounds__(64) void fold2_kernel(
    const float* __restrict__ W_d1, const float* __restrict__ P1T,
    float* __restrict__ Wd1oT) {
  const int row = blockIdx.x;
  const int lane = threadIdx.x;
  float acc[30];
#pragma unroll
  for (int n = 0; n < 30; ++n) acc[n] = 0.f;
  fold_row_T(W_d1 + (size_t)row * H_, P1T, H_, 0, acc, lane);
  reduce30_butterfly(acc);
  if (lane == 0) {
#pragma unroll
    for (int n = 0; n < 30; ++n) Wd1oT[(size_t)n * (3 * H_) + row] = acc[n];
  }
}

// ---------------------------------------------------------------------------
// fold3: Wf[row][n] = W_z[r,:] . Wd1oT[n, z*H..] (3072 blocks) + 3 bias blocks
// ---------------------------------------------------------------------------
__global__ __launch_bounds__(64) void fold3_kernel(
    const float* __restrict__ W_cls, const float* __restrict__ W_e1,
    const float* __restrict__ W_e2, const float* __restrict__ Wd1oT,
    const float* __restrict__ P1T, const float* __restrict__ WoutT,
    const float* __restrict__ b_cls, const float* __restrict__ b_e1,
    const float* __restrict__ b_e2, const float* __restrict__ b_d1,
    const float* __restrict__ b_d2,
    float* __restrict__ Wf, float* __restrict__ rbias) {
  const int lane = threadIdx.x;
  float acc[30];
#pragma unroll
  for (int n = 0; n < 30; ++n) acc[n] = 0.f;

  if (blockIdx.x < 3 * H_) {
    const int row = blockIdx.x;
    const int z = row >> 10, r = row & (H_ - 1);
    const float* A = (z == 0) ? W_cls : (z == 1) ? W_e1 : W_e2;
    fold_row_T(A + (size_t)r * H_, Wd1oT, 3 * H_, (size_t)z * H_, acc, lane);
    reduce30_butterfly(acc);
    if (lane == 0) {
#pragma unroll
      for (int n = 0; n < 30; ++n) Wf[(size_t)row * 32 + n] = acc[n];
    }
    return;
  }
  const int which = blockIdx.x - 3 * H_;
  if (which == 0) {
    // rbias[0..29] = [b_cls|b_e1|b_e2] . Wd1o  (K=3072, 12 coalesced chunks)
    float4 bv[12];
#pragma unroll
    for (int c = 0; c < 12; ++c) {
      const float* bsrc = (c < 4) ? (b_cls + c * 256)
                        : (c < 8) ? (b_e1 + (c - 4) * 256)
                                  : (b_e2 + (c - 8) * 256);
      bv[c] = *(const float4*)(bsrc + 4 * lane);
    }
    const float* sb = Wd1oT + 4 * lane;
#pragma unroll
    for (int n = 0; n < 30; ++n) {
      const float* srow = sb + (size_t)n * (3 * H_);
      float s = 0.f;
#pragma unroll
      for (int c = 0; c < 12; ++c) {
        float4 s4 = *(const float4*)(srow + c * 256);
        s += bv[c].x * s4.x + bv[c].y * s4.y + bv[c].z * s4.z + bv[c].w * s4.w;
      }
      acc[n] += s;
    }
    reduce30_butterfly(acc);
    if (lane == 0) {
#pragma unroll
      for (int n = 0; n < 30; ++n) rbias[n] = acc[n];
    }
  } else if (which == 1) {
    fold_row_T(b_d1, P1T, H_, 0, acc, lane);
    reduce30_butterfly(acc);
    if (lane == 0) {
#pragma unroll
      for (int n = 0; n < 30; ++n) rbias[32 + n] = acc[n];
    }
  } else {
    fold_row_T(b_d2, WoutT, H_, 0, acc, lane);
    reduce30_butterfly(acc);
    if (lane == 0) {
#pragma unroll
      for (int n = 0; n < 30; ++n) rbias[64 + n] = acc[n];
    }
  }
}

// ---------------------------------------------------------------------------
// Final: T[b] in LDS (tanh(x0), tanh(span means from partials)), then
// out[b][n] = T[b] . Wf[:,n] + btot[n].  grid B, block 256.
// ---------------------------------------------------------------------------
__global__ __launch_bounds__(256) void final_kernel(
    const float* __restrict__ x, const int* __restrict__ eidx,
    const float* __restrict__ Pspan, const float* __restrict__ Wf,
    const float* __restrict__ b_out, const float* __restrict__ rbias,
    float* __restrict__ out) {
  __shared__ float Ts[3 * H_];
  __shared__ float red[8][30];
  const int b = blockIdx.x;
  const int t = threadIdx.x;
  const int col = t * 4;

  {
    float4 v = *(const float4*)(x + (size_t)b * S_ * H_ + col);
    Ts[col + 0] = tanhf(v.x);
    Ts[col + 1] = tanhf(v.y);
    Ts[col + 2] = tanhf(v.z);
    Ts[col + 3] = tanhf(v.w);
  }
#pragma unroll
  for (int role = 0; role < 2; ++role) {
    const int lo = eidx[b * 4 + 2 * role];
    const int hi = eidx[b * 4 + 2 * role + 1];
    const int c0 = lo >> 6;
    const int c1 = (hi - 1) >> 6;
    float ax = 0.f, ay = 0.f, az = 0.f, aw = 0.f;
    for (int c = c0; c <= c1; ++c) {
      float4 v = *(const float4*)(Pspan + (((size_t)b * 2 + role) * NCHUNK + c) * H_ + col);
      ax += v.x; ay += v.y; az += v.z; aw += v.w;
    }
    const float inv = 1.0f / (float)(hi - lo);
    float* Td = Ts + (1 + role) * H_ + col;
    Td[0] = tanhf(ax * inv);
    Td[1] = tanhf(ay * inv);
    Td[2] = tanhf(az * inv);
    Td[3] = tanhf(aw * inv);
  }
  __syncthreads();

  if (t < 240) {
    const int n = t % 30, p = t / 30;
    const int k0 = p * 384;
    float s = 0.f;
#pragma unroll 4
    for (int k = k0; k < k0 + 384; ++k) s += Ts[k] * Wf[(size_t)k * 32 + n];
    red[p][n] = s;
  }
  __syncthreads();
  if (t < L_) {
    float s = b_out[t] + rbias[t] + rbias[32 + t] + rbias[64 + t];
#pragma unroll
    for (int p = 0; p < 8; ++p) s += red[p][t];
    out[(size_t)b * L_ + t] = s;
  }
}

extern "C" void kernel_launch(void* const* d_in, const int* in_sizes, int n_in,
                              void* d_out, int out_size, void* d_ws, size_t ws_size,
                              hipStream_t stream) {
  const float* x = (const float*)d_in[0];
  const int* eidx = (const int*)d_in[1];
  const float* W_cls = (const float*)d_in[2];
  const float* b_cls = (const float*)d_in[3];
  const float* W_e1 = (const float*)d_in[4];
  const float* b_e1 = (const float*)d_in[5];
  const float* W_e2 = (const float*)d_in[6];
  const float* b_e2 = (const float*)d_in[7];
  const float* W_d1 = (const float*)d_in[8];
  const float* b_d1 = (const float*)d_in[9];
  const float* W_d2 = (const float*)d_in[10];
  const float* b_d2 = (const float*)d_in[11];
  const float* W_out = (const float*)d_in[12];
  const float* b_out = (const float*)d_in[13];
  float* out = (float*)d_out;

  float* ws = (float*)d_ws;
  float* Pspan = ws;                   // 256*2*8*1024 = 4,194,304
  float* WoutT = Pspan + 4194304;      // 30*1024 = 30,720
  float* P1T   = WoutT + 30720;        // 30*1024 = 30,720
  float* Wd1oT = P1T + 30720;          // 30*3072 = 92,160
  float* Wf    = Wd1oT + 92160;        // 3072*32 = 98,304
  float* rbias = Wf + 98304;           // 96
  // total ~4.45M floats ~17.8 MB

  // span partials + W_out transpose tail
  span_kernel<<<dim3(B_, NCHUNK + 1, 2), 256, 0, stream>>>(
      x, eidx, W_out, Pspan, WoutT);

  fold1_kernel<<<H_, 64, 0, stream>>>(W_d2, WoutT, P1T);
  fold2_kernel<<<3 * H_, 64, 0, stream>>>(W_d1, P1T, Wd1oT);
  fold3_kernel<<<3 * H_ + 3, 64, 0, stream>>>(
      W_cls, W_e1, W_e2, Wd1oT, P1T, WoutT,
      b_cls, b_e1, b_e2, b_d1, b_d2, Wf, rbias);

  final_kernel<<<B_, 256, 0, stream>>>(x, eidx, Pspan, Wf, b_out, rbias, out);
}